// Round 4
// baseline (183.055 us; speedup 1.0000x reference)
//
#include <hip/hip_runtime.h>
#include <math.h>

#define NB 4
#define LQ 512
#define LK 512
#define DM 512
#define NH 8
#define DQ 64
#define NL 8

typedef short bf16x8 __attribute__((ext_vector_type(8)));
typedef float f32x4 __attribute__((ext_vector_type(4)));

__device__ __forceinline__ unsigned short f2bf(float x) {
    unsigned u = __float_as_uint(x);
    u += 0x7fff + ((u >> 16) & 1);          // RNE
    return (unsigned short)(u >> 16);
}
__device__ __forceinline__ float bf2f(unsigned x) {
    return __uint_as_float(x << 16);
}
__device__ __forceinline__ uint4 pack8(float4 a, float4 b) {
    uint4 o;
    o.x = (unsigned)f2bf(a.x) | ((unsigned)f2bf(a.y) << 16);
    o.y = (unsigned)f2bf(a.z) | ((unsigned)f2bf(a.w) << 16);
    o.z = (unsigned)f2bf(b.x) | ((unsigned)f2bf(b.y) << 16);
    o.w = (unsigned)f2bf(b.z) | ((unsigned)f2bf(b.w) << 16);
    return o;
}

// async global->LDS, 16B per lane. LDS dest is wave-uniform base + lane*16.
__device__ __forceinline__ void gld16(const void* g, void* l) {
    __builtin_amdgcn_global_load_lds(
        (const __attribute__((address_space(1))) void*)g,
        (__attribute__((address_space(3))) void*)l, 16, 0, 0);
}

// ---------------------------------------------------------------------------
// All three input projections, fp32 operands converted in-register.
// C[m,n] = sum_d A[m,d]*W[n,d] (+bias).  z: 0=Q, 1=K, 2=V-transposed.
// 64x64 tiles, 256 thr = 4 waves (2x2), MI=NI=2.  Grid (32,8,3).
// ---------------------------------------------------------------------------
__global__ __launch_bounds__(256) void proj_all(const float* __restrict__ qg,
                                                const float* __restrict__ kg,
                                                const float* __restrict__ wq,
                                                const float* __restrict__ wk,
                                                const float* __restrict__ wv,
                                                const float* __restrict__ w_q_b,
                                                unsigned short* __restrict__ Qp,
                                                unsigned short* __restrict__ Kp,
                                                unsigned short* __restrict__ Vt) {
    __shared__ __align__(16) short As[64 * 32];
    __shared__ __align__(16) short Bs[64 * 32];
    const float* A; const float* W; const float* bias; unsigned short* C; int mode;
    switch (blockIdx.z) {
        case 0:  A = qg; W = wq; bias = w_q_b;  C = Qp; mode = 0; break;
        case 1:  A = kg; W = wk; bias = nullptr; C = Kp; mode = 0; break;
        default: A = kg; W = wv; bias = nullptr; C = Vt; mode = 1; break;
    }
    const int tid = threadIdx.x, wave = tid >> 6, lane = tid & 63;
    const int quad = lane >> 4, l16 = lane & 15;
    const int wr = wave >> 1, wc = wave & 1;
    const int m0 = blockIdx.x * 64, n0 = blockIdx.y * 64;
    const int srow = tid >> 2, scol = (tid & 3) * 8;
    const float* Ab = A + (size_t)(m0 + srow) * DM + scol;
    const float* Wb = W + (size_t)(n0 + srow) * DM + scol;

    f32x4 acc[2][2];
    const f32x4 zz = {0.f, 0.f, 0.f, 0.f};
#pragma unroll
    for (int i = 0; i < 2; ++i)
#pragma unroll
        for (int j = 0; j < 2; ++j) acc[i][j] = zz;

    for (int k0 = 0; k0 < DM; k0 += 32) {
        const float4 a0 = *(const float4*)(Ab + k0);
        const float4 a1 = *(const float4*)(Ab + k0 + 4);
        const float4 b0 = *(const float4*)(Wb + k0);
        const float4 b1 = *(const float4*)(Wb + k0 + 4);
        __syncthreads();
        *(uint4*)&As[srow * 32 + scol] = pack8(a0, a1);
        *(uint4*)&Bs[srow * 32 + scol] = pack8(b0, b1);
        __syncthreads();
        bf16x8 af[2], bf[2];
#pragma unroll
        for (int i = 0; i < 2; ++i)
            af[i] = *(const bf16x8*)&As[(wr * 32 + i * 16 + l16) * 32 + quad * 8];
#pragma unroll
        for (int j = 0; j < 2; ++j)
            bf[j] = *(const bf16x8*)&Bs[(wc * 32 + j * 16 + l16) * 32 + quad * 8];
#pragma unroll
        for (int i = 0; i < 2; ++i)
#pragma unroll
            for (int j = 0; j < 2; ++j)
                acc[i][j] = __builtin_amdgcn_mfma_f32_16x16x32_bf16(af[i], bf[j], acc[i][j], 0, 0, 0);
    }
#pragma unroll
    for (int i = 0; i < 2; ++i)
#pragma unroll
        for (int r = 0; r < 4; ++r) {
            const int gm = m0 + wr * 32 + i * 16 + quad * 4 + r;
#pragma unroll
            for (int j = 0; j < 2; ++j) {
                const int gn = n0 + wc * 32 + j * 16 + l16;
                float v = acc[i][j][r];
                if (bias) v += bias[gn];
                if (mode == 0) C[(size_t)gm * DM + gn] = f2bf(v);
                else C[(size_t)(gm >> 9) * (DM * LK) + (size_t)gn * LK + (gm & 511)] = f2bf(v);
            }
        }
}

// ---------------------------------------------------------------------------
// QK^T per (h,b): K=64 single-shot.  128x128 tile, ALL staging issued, ONE
// barrier, then 32 MFMAs/wave.  Scores stored bf16.  Grid (4,4,32).
// ---------------------------------------------------------------------------
__global__ __launch_bounds__(256) void qk_mfma(const unsigned short* __restrict__ Qp,
                                               const unsigned short* __restrict__ Kp,
                                               unsigned short* __restrict__ Sc) {
    __shared__ __align__(16) short As[2][128 * 32];   // two 32-k slabs
    __shared__ __align__(16) short Bs[2][128 * 32];
    const int tid = threadIdx.x, wave = tid >> 6, lane = tid & 63;
    const int quad = lane >> 4, l16 = lane & 15;
    const int wr = wave >> 1, wc = wave & 1;
    const int z = blockIdx.z, h = z >> 2, b = z & 3;
    const int m0 = blockIdx.x * 128, n0 = blockIdx.y * 128;
    const unsigned short* Ag = Qp + (size_t)(b * LQ + m0) * DM + h * DQ;
    const unsigned short* Bg = Kp + (size_t)(b * LK + n0) * DM + h * DQ;

#pragma unroll
    for (int s = 0; s < 2; ++s)
#pragma unroll
        for (int it = 0; it < 2; ++it) {
            const int c = it * 256 + tid;            // row=c>>2, col8=(c&3)*8
            gld16(Ag + (size_t)(c >> 2) * DM + s * 32 + (c & 3) * 8,
                  (char*)As[s] + it * 4096 + wave * 1024);
            gld16(Bg + (size_t)(c >> 2) * DM + s * 32 + (c & 3) * 8,
                  (char*)Bs[s] + it * 4096 + wave * 1024);
        }
    __syncthreads();

    f32x4 acc[4][4];
    const f32x4 zz = {0.f, 0.f, 0.f, 0.f};
#pragma unroll
    for (int i = 0; i < 4; ++i)
#pragma unroll
        for (int j = 0; j < 4; ++j) acc[i][j] = zz;
#pragma unroll
    for (int s = 0; s < 2; ++s) {
        bf16x8 af[4], bf[4];
#pragma unroll
        for (int i = 0; i < 4; ++i)
            af[i] = *(const bf16x8*)&As[s][(wr * 64 + i * 16 + l16) * 32 + quad * 8];
#pragma unroll
        for (int j = 0; j < 4; ++j)
            bf[j] = *(const bf16x8*)&Bs[s][(wc * 64 + j * 16 + l16) * 32 + quad * 8];
#pragma unroll
        for (int i = 0; i < 4; ++i)
#pragma unroll
            for (int j = 0; j < 4; ++j)
                acc[i][j] = __builtin_amdgcn_mfma_f32_16x16x32_bf16(af[i], bf[j], acc[i][j], 0, 0, 0);
    }
    unsigned short* Cz = Sc + (size_t)z * LQ * LK;
#pragma unroll
    for (int i = 0; i < 4; ++i)
#pragma unroll
        for (int r = 0; r < 4; ++r) {
            const int gm = m0 + wr * 64 + i * 16 + quad * 4 + r;
#pragma unroll
            for (int j = 0; j < 4; ++j) {
                const int gn = n0 + wc * 64 + j * 16 + l16;
                Cz[(size_t)gm * LK + gn] = f2bf(acc[i][j][r]);
            }
        }
}

// ---------------------------------------------------------------------------
// Wave-per-head fused rel-score + mask + softmax + t.  512 thr = 8 waves =
// 8 heads of one (b,q) row.  Lane owns k = lane + 64*j (unit-stride).
// s[h,l] computed in-wave by shuffle reduction.  No LDS, no barriers.
// ---------------------------------------------------------------------------
__global__ __launch_bounds__(512) void softmax_kernel(const float* __restrict__ em,
                                                      const float* __restrict__ pad,
                                                      const unsigned short* __restrict__ Qp,
                                                      const float* __restrict__ b_ks,
                                                      const unsigned short* __restrict__ Sc,
                                                      float* __restrict__ weights,
                                                      unsigned short* __restrict__ attn,
                                                      float* __restrict__ Tb) {
    const int tid = threadIdx.x, wave = tid >> 6, lane = tid & 63;
    const int bq = blockIdx.x, b = bq >> 9, q = bq & 511;
    const int h = wave, z = h * NB + b;

    // s[l] = sum_d Qp[bq][h*64+d] * b_ks[l][d], lane = d, butterfly-reduce
    const float qd = bf2f(Qp[(size_t)bq * DM + h * DQ + lane]);
    float sv[NL];
#pragma unroll
    for (int l = 0; l < NL; ++l) {
        float p = qd * b_ks[l * DQ + lane];
#pragma unroll
        for (int o = 1; o < 64; o <<= 1) p += __shfl_xor(p, o, 64);
        sv[l] = p;
    }

    float4 ev[16];
    const float* eb = em + (size_t)bq * (LK * NL);
#pragma unroll
    for (int j = 0; j < 8; ++j) {
        const int k = lane + 64 * j;
        ev[2 * j]     = *(const float4*)(eb + k * 8);
        ev[2 * j + 1] = *(const float4*)(eb + k * 8 + 4);
    }
    float padv[8];
#pragma unroll
    for (int j = 0; j < 8; ++j) padv[j] = pad[(size_t)bq * LK + lane + 64 * j];
    const unsigned short* sp = Sc + ((size_t)z * LQ + q) * LK;
    float qk8[8];
#pragma unroll
    for (int j = 0; j < 8; ++j) qk8[j] = bf2f(sp[lane + 64 * j]);

    const size_t rowbase = ((size_t)z * LQ + q) * LK;
    float wv8[8], m8[8];
#pragma unroll
    for (int j = 0; j < 8; ++j) {
        const float4 a = ev[2 * j], c = ev[2 * j + 1];
        const float rel = a.x * sv[0] + a.y * sv[1] + a.z * sv[2] + a.w * sv[3]
                        + c.x * sv[4] + c.y * sv[5] + c.z * sv[6] + c.w * sv[7];
        const float es = ((a.x + a.y) + (a.z + a.w)) + ((c.x + c.y) + (c.z + c.w));
        const float wv = (qk8[j] + rel) * 0.125f;
        wv8[j] = wv;
        m8[j] = ((es + 1.0f - padv[j]) == 0.0f) ? -__builtin_inff() : wv;
        weights[rowbase + lane + 64 * j] = wv;          // pre-mask weights output
    }

    float mx = m8[0];
#pragma unroll
    for (int j = 1; j < 8; ++j) mx = fmaxf(mx, m8[j]);
#pragma unroll
    for (int o = 1; o < 64; o <<= 1) mx = fmaxf(mx, __shfl_xor(mx, o, 64));

    float e8[8], ss = 0.f;
#pragma unroll
    for (int j = 0; j < 8; ++j) { e8[j] = __expf(m8[j] - mx); ss += e8[j]; }
#pragma unroll
    for (int o = 1; o < 64; o <<= 1) ss += __shfl_xor(ss, o, 64);
    const float inv = 1.0f / ss;

    float tl[NL] = {0.f, 0.f, 0.f, 0.f, 0.f, 0.f, 0.f, 0.f};
#pragma unroll
    for (int j = 0; j < 8; ++j) {
        const float a_ = e8[j] * inv;                   // masked -> exactly 0
        attn[rowbase + lane + 64 * j] = f2bf(a_);
        const float4 a = ev[2 * j], c = ev[2 * j + 1];
        tl[0] = fmaf(a_, a.x, tl[0]); tl[1] = fmaf(a_, a.y, tl[1]);
        tl[2] = fmaf(a_, a.z, tl[2]); tl[3] = fmaf(a_, a.w, tl[3]);
        tl[4] = fmaf(a_, c.x, tl[4]); tl[5] = fmaf(a_, c.y, tl[5]);
        tl[6] = fmaf(a_, c.z, tl[6]); tl[7] = fmaf(a_, c.w, tl[7]);
    }
#pragma unroll
    for (int o = 1; o < 64; o <<= 1)
#pragma unroll
        for (int l = 0; l < NL; ++l) tl[l] += __shfl_xor(tl[l], o, 64);
    if (lane == 0) {
        float* tp = Tb + ((size_t)z * LQ + q) * NL;
#pragma unroll
        for (int l = 0; l < NL; ++l) tp[l] = tl[l];
    }
}

// ---------------------------------------------------------------------------
// qv + qvr:  Hb[b][q][h*64+d] = sum_k attn*Vt + sum_l t[l]*b_vs[l][d]
// 64x64 tile, 512 thr = 8 waves (2 on m x 4 on n): MI=2, NI=1.
// Waves 0-3 stage A, waves 4-7 stage B.  Grid (8,1,32) = 256 blocks.
// ---------------------------------------------------------------------------
__global__ __launch_bounds__(512) void qv_mfma(const unsigned short* __restrict__ Attn,
                                               const unsigned short* __restrict__ Vt,
                                               const float* __restrict__ Tb,
                                               const float* __restrict__ b_vs,
                                               unsigned short* __restrict__ Hb) {
    __shared__ __align__(16) short As[64 * 32];
    __shared__ __align__(16) short Bs[64 * 32];
    const int tid = threadIdx.x, wave = tid >> 6, lane = tid & 63;
    const int quad = lane >> 4, l16 = lane & 15;
    const int wr = wave >> 2, wc = wave & 3;
    const int z = blockIdx.z, h = z >> 2, b = z & 3;
    const int m0 = blockIdx.x * 64;
    const unsigned short* Ag = Attn + (size_t)z * LQ * LK + (size_t)m0 * LK;
    const unsigned short* Bg = Vt + (size_t)b * (DM * LK) + (size_t)(h * DQ) * LK;

    f32x4 acc[2];
    const f32x4 zz = {0.f, 0.f, 0.f, 0.f};
    acc[0] = zz; acc[1] = zz;
    const int c = tid & 255;              // staging chunk within the half

    for (int k0 = 0; k0 < LK; k0 += 32) {
        __syncthreads();
        if (tid < 256)
            gld16(Ag + (size_t)(c >> 2) * LK + k0 + (c & 3) * 8,
                  (char*)As + wave * 1024);
        else
            gld16(Bg + (size_t)(c >> 2) * LK + k0 + (c & 3) * 8,
                  (char*)Bs + (wave - 4) * 1024);
        __syncthreads();
        bf16x8 af[2], bf;
#pragma unroll
        for (int i = 0; i < 2; ++i)
            af[i] = *(const bf16x8*)&As[(wr * 32 + i * 16 + l16) * 32 + quad * 8];
        bf = *(const bf16x8*)&Bs[(wc * 16 + l16) * 32 + quad * 8];
#pragma unroll
        for (int i = 0; i < 2; ++i)
            acc[i] = __builtin_amdgcn_mfma_f32_16x16x32_bf16(af[i], bf, acc[i], 0, 0, 0);
    }
    const int d = wc * 16 + l16;
    float bvv[NL];
#pragma unroll
    for (int l = 0; l < NL; ++l) bvv[l] = b_vs[l * DQ + d];
#pragma unroll
    for (int i = 0; i < 2; ++i)
#pragma unroll
        for (int r = 0; r < 4; ++r) {
            const int qrow = m0 + wr * 32 + i * 16 + quad * 4 + r;
            const float* t8 = Tb + ((size_t)z * LQ + qrow) * NL;
            float qvr = 0.f;
#pragma unroll
            for (int l = 0; l < NL; ++l) qvr = fmaf(t8[l], bvv[l], qvr);
            Hb[(size_t)(b * LQ + qrow) * DM + h * DQ + d] = f2bf(acc[i][r] + qvr);
        }
}

// ---------------------------------------------------------------------------
// Output projection: A = Hb (bf16, gld16 path), W = w_h_w (fp32, convert
// path).  fp32 store + bias.  64x64 tiles -> grid (32, 8).
// ---------------------------------------------------------------------------
__global__ __launch_bounds__(256) void outproj_mfma(const unsigned short* __restrict__ Hb,
                                                    const float* __restrict__ W,
                                                    const float* __restrict__ bias,
                                                    float* __restrict__ C) {
    __shared__ __align__(16) short As[64 * 32];
    __shared__ __align__(16) short Bs[64 * 32];
    const int tid = threadIdx.x, wave = tid >> 6, lane = tid & 63;
    const int quad = lane >> 4, l16 = lane & 15;
    const int wr = wave >> 1, wc = wave & 1;
    const int m0 = blockIdx.x * 64, n0 = blockIdx.y * 64;
    const int srow = tid >> 2, scol = (tid & 3) * 8;
    const unsigned short* Ag = Hb + (size_t)m0 * DM;
    const float* Wb = W + (size_t)(n0 + srow) * DM + scol;

    f32x4 acc[2][2];
    const f32x4 zz = {0.f, 0.f, 0.f, 0.f};
#pragma unroll
    for (int i = 0; i < 2; ++i)
#pragma unroll
        for (int j = 0; j < 2; ++j) acc[i][j] = zz;

    for (int k0 = 0; k0 < DM; k0 += 32) {
        const float4 b0 = *(const float4*)(Wb + k0);
        const float4 b1 = *(const float4*)(Wb + k0 + 4);
        __syncthreads();
        gld16(Ag + (size_t)(tid >> 2) * DM + k0 + (tid & 3) * 8,
              (char*)As + wave * 1024);
        *(uint4*)&Bs[srow * 32 + scol] = pack8(b0, b1);
        __syncthreads();
        bf16x8 af[2], bf[2];
#pragma unroll
        for (int i = 0; i < 2; ++i)
            af[i] = *(const bf16x8*)&As[(wr * 32 + i * 16 + l16) * 32 + quad * 8];
#pragma unroll
        for (int j = 0; j < 2; ++j)
            bf[j] = *(const bf16x8*)&Bs[(wc * 32 + j * 16 + l16) * 32 + quad * 8];
#pragma unroll
        for (int i = 0; i < 2; ++i)
#pragma unroll
            for (int j = 0; j < 2; ++j)
                acc[i][j] = __builtin_amdgcn_mfma_f32_16x16x32_bf16(af[i], bf[j], acc[i][j], 0, 0, 0);
    }
#pragma unroll
    for (int i = 0; i < 2; ++i)
#pragma unroll
        for (int r = 0; r < 4; ++r) {
            const int gm = m0 + wr * 32 + i * 16 + quad * 4 + r;
#pragma unroll
            for (int j = 0; j < 2; ++j) {
                const int gn = n0 + wc * 32 + j * 16 + l16;
                C[(size_t)gm * DM + gn] = acc[i][j][r] + bias[gn];
            }
        }
}

// ---------------------------------------------------------------------------
extern "C" void kernel_launch(void* const* d_in, const int* in_sizes, int n_in,
                              void* d_out, int out_size, void* d_ws, size_t ws_size,
                              hipStream_t stream) {
    const float* q     = (const float*)d_in[0];
    const float* k     = (const float*)d_in[1];
    const float* em    = (const float*)d_in[2];
    const float* pad   = (const float*)d_in[3];
    const float* w_q_w = (const float*)d_in[4];
    const float* w_q_b = (const float*)d_in[5];
    const float* w_k   = (const float*)d_in[6];
    const float* w_v   = (const float*)d_in[7];
    const float* w_h_w = (const float*)d_in[8];
    const float* w_h_b = (const float*)d_in[9];
    const float* b_ks  = (const float*)d_in[10];
    const float* b_vs  = (const float*)d_in[11];

    float* out     = (float*)d_out;                       // (B, LQ, DM) fp32
    float* weights = out + (size_t)NB * LQ * DM;          // (H*B, LQ, LK) fp32

    char* ws = (char*)d_ws;                               // byte offsets (16B-aligned)
    unsigned short* Qp  = (unsigned short*)(ws + 0);          // 2 MB
    unsigned short* Kp  = (unsigned short*)(ws + 2097152);    // 2 MB
    unsigned short* Vt  = (unsigned short*)(ws + 4194304);    // 2 MB
    unsigned short* Hb  = (unsigned short*)(ws + 6291456);    // 2 MB
    unsigned short* Att = (unsigned short*)(ws + 8388608);    // 16 MB
    unsigned short* Sc  = (unsigned short*)(ws + 25165824);   // 16 MB
    float*          Tb  = (float*)(ws + 41943040);            // 512 KB

    proj_all<<<dim3(32, 8, 3), 256, 0, stream>>>(q, k, w_q_w, w_k, w_v, w_q_b, Qp, Kp, Vt);
    qk_mfma<<<dim3(4, 4, 32), 256, 0, stream>>>(Qp, Kp, Sc);
    softmax_kernel<<<dim3(NB * LQ), dim3(512), 0, stream>>>(em, pad, Qp, b_ks, Sc,
                                                            weights, Att, Tb);
    qv_mfma<<<dim3(8, 1, 32), 512, 0, stream>>>(Att, Vt, Tb, b_vs, Hb);
    outproj_mfma<<<dim3(32, 8), 256, 0, stream>>>(Hb, w_h_w, w_h_b, out);
}

// Round 5
// 176.046 us; speedup vs baseline: 1.0398x; 1.0398x over previous
//
#include <hip/hip_runtime.h>
#include <math.h>

#define NB 4
#define LQ 512
#define LK 512
#define DM 512
#define NH 8
#define DQ 64
#define NL 8
#define QT 32          // q-rows per attn block
#define PSTR 520       // Ps row stride in shorts (pad vs 512 to break bank aliasing)

typedef short bf16x8 __attribute__((ext_vector_type(8)));
typedef float f32x4 __attribute__((ext_vector_type(4)));

__device__ __forceinline__ unsigned short f2bf(float x) {
    unsigned u = __float_as_uint(x);
    u += 0x7fff + ((u >> 16) & 1);          // RNE
    return (unsigned short)(u >> 16);
}
__device__ __forceinline__ float bf2f(unsigned x) {
    return __uint_as_float(x << 16);
}
__device__ __forceinline__ uint4 pack8(float4 a, float4 b) {
    uint4 o;
    o.x = (unsigned)f2bf(a.x) | ((unsigned)f2bf(a.y) << 16);
    o.y = (unsigned)f2bf(a.z) | ((unsigned)f2bf(a.w) << 16);
    o.z = (unsigned)f2bf(b.x) | ((unsigned)f2bf(b.y) << 16);
    o.w = (unsigned)f2bf(b.z) | ((unsigned)f2bf(b.w) << 16);
    return o;
}
// async global->LDS, 16B/lane; LDS dest = wave-uniform base + lane*16
__device__ __forceinline__ void gld16(const void* g, void* l) {
    __builtin_amdgcn_global_load_lds(
        (const __attribute__((address_space(1))) void*)g,
        (__attribute__((address_space(3))) void*)l, 16, 0, 0);
}

// ---------------------------------------------------------------------------
// Pack em (0/1 floats) + pad into 9-bit words: bits 0-7 = em[l], bit 8 = pad.
// Grid (NB*LQ), 256 thr, thread handles 2 consecutive k.
// ---------------------------------------------------------------------------
__global__ __launch_bounds__(256) void empack_kernel(const float* __restrict__ em,
                                                     const float* __restrict__ pad,
                                                     unsigned short* __restrict__ Pk) {
    const int bq = blockIdx.x;
    const int k0 = threadIdx.x * 2;
    const float4* e4 = (const float4*)(em + (size_t)bq * (LK * NL) + (size_t)k0 * NL);
    const float4 v0 = e4[0], v1 = e4[1], v2 = e4[2], v3 = e4[3];
    const float2 pv = *(const float2*)(pad + (size_t)bq * LK + k0);
    unsigned b0 = 0, b1 = 0;
    b0 |= (v0.x != 0.f) << 0; b0 |= (v0.y != 0.f) << 1;
    b0 |= (v0.z != 0.f) << 2; b0 |= (v0.w != 0.f) << 3;
    b0 |= (v1.x != 0.f) << 4; b0 |= (v1.y != 0.f) << 5;
    b0 |= (v1.z != 0.f) << 6; b0 |= (v1.w != 0.f) << 7;
    b0 |= (pv.x != 0.f) << 8;
    b1 |= (v2.x != 0.f) << 0; b1 |= (v2.y != 0.f) << 1;
    b1 |= (v2.z != 0.f) << 2; b1 |= (v2.w != 0.f) << 3;
    b1 |= (v3.x != 0.f) << 4; b1 |= (v3.y != 0.f) << 5;
    b1 |= (v3.z != 0.f) << 6; b1 |= (v3.w != 0.f) << 7;
    b1 |= (pv.y != 0.f) << 8;
    *(unsigned*)(Pk + (size_t)bq * LK + k0) = b0 | (b1 << 16);
}

// ---------------------------------------------------------------------------
// All three input projections, fp32 operands converted in-register.
// z: 0=Q, 1=K, 2=V-transposed.  64x64 tiles, 256 thr.  Grid (32,8,3).
// ---------------------------------------------------------------------------
__global__ __launch_bounds__(256) void proj_all(const float* __restrict__ qg,
                                                const float* __restrict__ kg,
                                                const float* __restrict__ wq,
                                                const float* __restrict__ wk,
                                                const float* __restrict__ wv,
                                                const float* __restrict__ w_q_b,
                                                unsigned short* __restrict__ Qp,
                                                unsigned short* __restrict__ Kp,
                                                unsigned short* __restrict__ Vt) {
    __shared__ __align__(16) short As[64 * 32];
    __shared__ __align__(16) short Bs[64 * 32];
    const float* A; const float* W; const float* bias; unsigned short* C; int mode;
    switch (blockIdx.z) {
        case 0:  A = qg; W = wq; bias = w_q_b;  C = Qp; mode = 0; break;
        case 1:  A = kg; W = wk; bias = nullptr; C = Kp; mode = 0; break;
        default: A = kg; W = wv; bias = nullptr; C = Vt; mode = 1; break;
    }
    const int tid = threadIdx.x, wave = tid >> 6, lane = tid & 63;
    const int quad = lane >> 4, l16 = lane & 15;
    const int wr = wave >> 1, wc = wave & 1;
    const int m0 = blockIdx.x * 64, n0 = blockIdx.y * 64;
    const int srow = tid >> 2, scol = (tid & 3) * 8;
    const float* Ab = A + (size_t)(m0 + srow) * DM + scol;
    const float* Wb = W + (size_t)(n0 + srow) * DM + scol;

    f32x4 acc[2][2];
    const f32x4 zz = {0.f, 0.f, 0.f, 0.f};
#pragma unroll
    for (int i = 0; i < 2; ++i)
#pragma unroll
        for (int j = 0; j < 2; ++j) acc[i][j] = zz;

    for (int k0 = 0; k0 < DM; k0 += 32) {
        const float4 a0 = *(const float4*)(Ab + k0);
        const float4 a1 = *(const float4*)(Ab + k0 + 4);
        const float4 b0 = *(const float4*)(Wb + k0);
        const float4 b1 = *(const float4*)(Wb + k0 + 4);
        __syncthreads();
        *(uint4*)&As[srow * 32 + scol] = pack8(a0, a1);
        *(uint4*)&Bs[srow * 32 + scol] = pack8(b0, b1);
        __syncthreads();
        bf16x8 af[2], bf[2];
#pragma unroll
        for (int i = 0; i < 2; ++i)
            af[i] = *(const bf16x8*)&As[(wr * 32 + i * 16 + l16) * 32 + quad * 8];
#pragma unroll
        for (int j = 0; j < 2; ++j)
            bf[j] = *(const bf16x8*)&Bs[(wc * 32 + j * 16 + l16) * 32 + quad * 8];
#pragma unroll
        for (int i = 0; i < 2; ++i)
#pragma unroll
            for (int j = 0; j < 2; ++j)
                acc[i][j] = __builtin_amdgcn_mfma_f32_16x16x32_bf16(af[i], bf[j], acc[i][j], 0, 0, 0);
    }
#pragma unroll
    for (int i = 0; i < 2; ++i)
#pragma unroll
        for (int r = 0; r < 4; ++r) {
            const int gm = m0 + wr * 32 + i * 16 + quad * 4 + r;
#pragma unroll
            for (int j = 0; j < 2; ++j) {
                const int gn = n0 + wc * 32 + j * 16 + l16;
                float v = acc[i][j][r];
                if (bias) v += bias[gn];
                if (mode == 0) C[(size_t)gm * DM + gn] = f2bf(v);
                else C[(size_t)(gm >> 9) * (DM * LK) + (size_t)gn * LK + (gm & 511)] = f2bf(v);
            }
        }
}

// ---------------------------------------------------------------------------
// Fused attention: QK^T -> rel+mask -> weights write -> softmax -> attn ->
// (attn @ V) + qvr, all in one block per (z = h*4+b, 32-q-row tile).
// 512 thr = 8 waves.  Wave w owns k-columns {c*128 + w*16 + l16} of S.
// K and V streamed through one 16 KB LDS chunk buffer.
// Grid (16, 32).
// ---------------------------------------------------------------------------
__global__ __launch_bounds__(512, 4) void attn_fused(
        const unsigned short* __restrict__ Qp,
        const unsigned short* __restrict__ Kp,
        const unsigned short* __restrict__ Vt,
        const unsigned short* __restrict__ Pk,
        const float* __restrict__ b_ks,
        const float* __restrict__ b_vs,
        float* __restrict__ weights,
        unsigned short* __restrict__ Hb) {
    __shared__ __align__(16) short Qs[QT * 64];       // 4 KB   Q tile [q][d]
    __shared__ __align__(16) short Kc[128 * 64];      // 16 KB  K chunk [k][d] / V chunk [d][k]
    __shared__ __align__(16) short Ps[QT * PSTR];     // 32.5KB attn [q][k] bf16
    __shared__ float svS[QT * NL];
    __shared__ float tS[QT * NL];
    __shared__ float redA[QT * 8];
    __shared__ float redB[QT * 8];

    const int tid = threadIdx.x, wave = tid >> 6, lane = tid & 63;
    const int quad = lane >> 4, l16 = lane & 15;
    const int q0 = blockIdx.x * QT;
    const int z = blockIdx.y, h = z >> 2, b = z & 3;

    // ---- stage Q tile (32 rows x 64 d, head h) ----
    if (tid < 256) {
        const int row = tid >> 3, off = (tid & 7) * 8;
        gld16(Qp + (size_t)(b * LQ + q0 + row) * DM + h * DQ + off,
              (char*)Qs + wave * 1024);
    }

    // ---- QK^T: S[32 x 512] in 4 chunks of 128 k-rows ----
    f32x4 acc[4][2];
    const f32x4 zz = {0.f, 0.f, 0.f, 0.f};
#pragma unroll
    for (int c = 0; c < 4; ++c) { acc[c][0] = zz; acc[c][1] = zz; }

    for (int c = 0; c < 4; ++c) {
#pragma unroll
        for (int it = 0; it < 2; ++it) {
            const int e = it * 512 + tid;
            const int kr = c * 128 + (e >> 3), off = (e & 7) * 8;
            gld16(Kp + (size_t)(b * LK + kr) * DM + h * DQ + off,
                  (char*)Kc + it * 8192 + wave * 1024);
        }
        __syncthreads();
#pragma unroll
        for (int kd = 0; kd < 64; kd += 32) {
            const bf16x8 bfv = *(const bf16x8*)&Kc[(wave * 16 + l16) * 64 + kd + quad * 8];
#pragma unroll
            for (int i = 0; i < 2; ++i) {
                const bf16x8 afv = *(const bf16x8*)&Qs[(i * 16 + l16) * 64 + kd + quad * 8];
                acc[c][i] = __builtin_amdgcn_mfma_f32_16x16x32_bf16(afv, bfv, acc[c][i], 0, 0, 0);
            }
        }
        if (c == 0 && tid < 256) {
            // sv[row][l] = sum_d Q[row][d] * b_ks[l][d]
            const int row = tid >> 3, l = tid & 7;
            float s = 0.f;
#pragma unroll
            for (int d = 0; d < DQ; ++d)
                s = fmaf(bf2f((unsigned short)Qs[row * 64 + d]), b_ks[l * DQ + d], s);
            svS[row * 8 + l] = s;
        }
        __syncthreads();
    }

    // ---- prefetch V chunk 0 (Kc is free); lands during the long epilogue ----
#pragma unroll
    for (int it = 0; it < 2; ++it) {
        const int e = it * 512 + tid;
        const int dd = e >> 4, off = (e & 15) * 8;
        gld16(Vt + (size_t)(b * DM + h * DQ + dd) * LK + off,
              (char*)Kc + it * 8192 + wave * 1024);
    }

    // ---- epilogue A: rel + mask + weights write + m (in acc), rowmax partials
#pragma unroll
    for (int i = 0; i < 2; ++i)
#pragma unroll
        for (int r = 0; r < 4; ++r) {
            const int row = i * 16 + quad * 4 + r;
            const int gq = q0 + row;
            const f32x4 sv0 = *(const f32x4*)&svS[row * 8];
            const f32x4 sv1 = *(const f32x4*)&svS[row * 8 + 4];
            const unsigned short* prow = Pk + (size_t)(b * LQ + gq) * LK;
            float* wrow = weights + ((size_t)z * LQ + gq) * LK;
            float pm = -__builtin_inff();
#pragma unroll
            for (int c = 0; c < 4; ++c) {
                const int col = c * 128 + wave * 16 + l16;
                const unsigned w_ = prow[col];
                float rel = 0.f;
                rel = fmaf((float)((w_ >> 0) & 1), sv0[0], rel);
                rel = fmaf((float)((w_ >> 1) & 1), sv0[1], rel);
                rel = fmaf((float)((w_ >> 2) & 1), sv0[2], rel);
                rel = fmaf((float)((w_ >> 3) & 1), sv0[3], rel);
                rel = fmaf((float)((w_ >> 4) & 1), sv1[0], rel);
                rel = fmaf((float)((w_ >> 5) & 1), sv1[1], rel);
                rel = fmaf((float)((w_ >> 6) & 1), sv1[2], rel);
                rel = fmaf((float)((w_ >> 7) & 1), sv1[3], rel);
                const float wv = (acc[c][i][r] + rel) * 0.125f;
                wrow[col] = wv;                               // pre-mask weights
                const float m = ((w_ & 0x1FFu) == 0x100u) ? -__builtin_inff() : wv;
                acc[c][i][r] = m;
                pm = fmaxf(pm, m);
            }
#pragma unroll
            for (int o = 1; o < 16; o <<= 1) pm = fmaxf(pm, __shfl_xor(pm, o, 64));
            if (l16 == 0) redA[row * 8 + wave] = pm;
        }
    __syncthreads();

    // ---- epilogue B: exp + rowsum partials ----
#pragma unroll
    for (int i = 0; i < 2; ++i)
#pragma unroll
        for (int r = 0; r < 4; ++r) {
            const int row = i * 16 + quad * 4 + r;
            const f32x4 ra = *(const f32x4*)&redA[row * 8];
            const f32x4 rb = *(const f32x4*)&redA[row * 8 + 4];
            const float rmax = fmaxf(fmaxf(fmaxf(ra[0], ra[1]), fmaxf(ra[2], ra[3])),
                                     fmaxf(fmaxf(rb[0], rb[1]), fmaxf(rb[2], rb[3])));
            float psum = 0.f;
#pragma unroll
            for (int c = 0; c < 4; ++c) {
                const float e = __expf(acc[c][i][r] - rmax);
                acc[c][i][r] = e;
                psum += e;
            }
#pragma unroll
            for (int o = 1; o < 16; o <<= 1) psum += __shfl_xor(psum, o, 64);
            if (l16 == 0) redB[row * 8 + wave] = psum;
        }
    __syncthreads();

    // ---- epilogue C: normalize, write attn into Ps (A-operand layout) ----
#pragma unroll
    for (int i = 0; i < 2; ++i)
#pragma unroll
        for (int r = 0; r < 4; ++r) {
            const int row = i * 16 + quad * 4 + r;
            const f32x4 sa = *(const f32x4*)&redB[row * 8];
            const f32x4 sb = *(const f32x4*)&redB[row * 8 + 4];
            const float tot = ((sa[0] + sa[1]) + (sa[2] + sa[3])) +
                              ((sb[0] + sb[1]) + (sb[2] + sb[3]));
            const float inv = 1.0f / tot;
#pragma unroll
            for (int c = 0; c < 4; ++c) {
                const int col = c * 128 + wave * 16 + l16;
                Ps[row * PSTR + col] = (short)f2bf(acc[c][i][r] * inv);
            }
        }
    __syncthreads();   // Ps visible; V chunk 0 resident (vmcnt drained)

    // ---- t[q][l] = sum_k attn[q,k] * em_bit_l[q,k] ----
    {
        const int row = tid >> 4, l = (tid >> 1) & 7, half = tid & 1;
        const unsigned* pw = (const unsigned*)(Pk + (size_t)(b * LQ + q0 + row) * LK + half * 256);
        const unsigned* aw = (const unsigned*)&Ps[row * PSTR + half * 256];
        float tv = 0.f;
#pragma unroll 4
        for (int kk = 0; kk < 128; ++kk) {
            const unsigned wbits = pw[kk];
            const unsigned av = aw[kk];
            tv = fmaf((float)((wbits >> l) & 1),        bf2f(av & 0xffffu), tv);
            tv = fmaf((float)((wbits >> (16 + l)) & 1), bf2f(av >> 16), tv);
        }
        tv += __shfl_xor(tv, 1, 64);
        if (half == 0) tS[row * 8 + l] = tv;
    }

    // ---- PV: O[32 x 64] = attn @ V, V streamed in 4 chunks of 128 k ----
    f32x4 oacc = zz;
    const int mi = wave & 1, ni = wave >> 1;
    for (int vc = 0; vc < 4; ++vc) {
        if (vc > 0) {
            __syncthreads();                         // prev chunk reads done
#pragma unroll
            for (int it = 0; it < 2; ++it) {
                const int e = it * 512 + tid;
                const int dd = e >> 4, off = (e & 15) * 8;
                gld16(Vt + (size_t)(b * DM + h * DQ + dd) * LK + vc * 128 + off,
                      (char*)Kc + it * 8192 + wave * 1024);
            }
        }
        __syncthreads();                             // chunk vc resident (+tS fence at vc=0)
#pragma unroll
        for (int kd = 0; kd < 128; kd += 32) {
            const bf16x8 afv = *(const bf16x8*)&Ps[(mi * 16 + l16) * PSTR + vc * 128 + kd + quad * 8];
            const bf16x8 bfv = *(const bf16x8*)&Kc[(ni * 16 + l16) * 128 + kd + quad * 8];
            oacc = __builtin_amdgcn_mfma_f32_16x16x32_bf16(afv, bfv, oacc, 0, 0, 0);
        }
    }

    // ---- output epilogue: + qvr, store Hb bf16 ----
    const int gd = ni * 16 + l16;
    float bvv[NL];
#pragma unroll
    for (int l = 0; l < NL; ++l) bvv[l] = b_vs[l * DQ + gd];
#pragma unroll
    for (int r = 0; r < 4; ++r) {
        const int row = mi * 16 + quad * 4 + r;
        const float* tp = &tS[row * 8];
        float o = oacc[r];
#pragma unroll
        for (int l = 0; l < NL; ++l) o = fmaf(tp[l], bvv[l], o);
        Hb[(size_t)(b * LQ + q0 + row) * DM + h * DQ + gd] = f2bf(o);
    }
}

// ---------------------------------------------------------------------------
// Output projection: A = Hb (bf16, gld16 path), W fp32 (convert path).
// fp32 store + bias.  64x64 tiles -> grid (32, 8).
// ---------------------------------------------------------------------------
__global__ __launch_bounds__(256) void outproj_mfma(const unsigned short* __restrict__ Hb,
                                                    const float* __restrict__ W,
                                                    const float* __restrict__ bias,
                                                    float* __restrict__ C) {
    __shared__ __align__(16) short As[64 * 32];
    __shared__ __align__(16) short Bs[64 * 32];
    const int tid = threadIdx.x, wave = tid >> 6, lane = tid & 63;
    const int quad = lane >> 4, l16 = lane & 15;
    const int wr = wave >> 1, wc = wave & 1;
    const int m0 = blockIdx.x * 64, n0 = blockIdx.y * 64;
    const int srow = tid >> 2, scol = (tid & 3) * 8;
    const unsigned short* Ag = Hb + (size_t)m0 * DM;
    const float* Wb = W + (size_t)(n0 + srow) * DM + scol;

    f32x4 acc[2][2];
    const f32x4 zz = {0.f, 0.f, 0.f, 0.f};
#pragma unroll
    for (int i = 0; i < 2; ++i)
#pragma unroll
        for (int j = 0; j < 2; ++j) acc[i][j] = zz;

    for (int k0 = 0; k0 < DM; k0 += 32) {
        const float4 b0 = *(const float4*)(Wb + k0);
        const float4 b1 = *(const float4*)(Wb + k0 + 4);
        __syncthreads();
        gld16(Ag + (size_t)(tid >> 2) * DM + k0 + (tid & 3) * 8,
              (char*)As + wave * 1024);
        *(uint4*)&Bs[srow * 32 + scol] = pack8(b0, b1);
        __syncthreads();
        bf16x8 af[2], bf[2];
#pragma unroll
        for (int i = 0; i < 2; ++i)
            af[i] = *(const bf16x8*)&As[(wr * 32 + i * 16 + l16) * 32 + quad * 8];
#pragma unroll
        for (int j = 0; j < 2; ++j)
            bf[j] = *(const bf16x8*)&Bs[(wc * 32 + j * 16 + l16) * 32 + quad * 8];
#pragma unroll
        for (int i = 0; i < 2; ++i)
#pragma unroll
            for (int j = 0; j < 2; ++j)
                acc[i][j] = __builtin_amdgcn_mfma_f32_16x16x32_bf16(af[i], bf[j], acc[i][j], 0, 0, 0);
    }
#pragma unroll
    for (int i = 0; i < 2; ++i)
#pragma unroll
        for (int r = 0; r < 4; ++r) {
            const int gm = m0 + wr * 32 + i * 16 + quad * 4 + r;
#pragma unroll
            for (int j = 0; j < 2; ++j) {
                const int gn = n0 + wc * 32 + j * 16 + l16;
                C[(size_t)gm * DM + gn] = acc[i][j][r] + bias[gn];
            }
        }
}

// ---------------------------------------------------------------------------
extern "C" void kernel_launch(void* const* d_in, const int* in_sizes, int n_in,
                              void* d_out, int out_size, void* d_ws, size_t ws_size,
                              hipStream_t stream) {
    const float* q     = (const float*)d_in[0];
    const float* k     = (const float*)d_in[1];
    const float* em    = (const float*)d_in[2];
    const float* pad   = (const float*)d_in[3];
    const float* w_q_w = (const float*)d_in[4];
    const float* w_q_b = (const float*)d_in[5];
    const float* w_k   = (const float*)d_in[6];
    const float* w_v   = (const float*)d_in[7];
    const float* w_h_w = (const float*)d_in[8];
    const float* w_h_b = (const float*)d_in[9];
    const float* b_ks  = (const float*)d_in[10];
    const float* b_vs  = (const float*)d_in[11];

    float* out     = (float*)d_out;                       // (B, LQ, DM) fp32
    float* weights = out + (size_t)NB * LQ * DM;          // (H*B, LQ, LK) fp32

    char* ws = (char*)d_ws;
    unsigned short* Qp = (unsigned short*)(ws + 0);           // 2 MB
    unsigned short* Kp = (unsigned short*)(ws + 2097152);     // 2 MB
    unsigned short* Vt = (unsigned short*)(ws + 4194304);     // 2 MB
    unsigned short* Hb = (unsigned short*)(ws + 6291456);     // 2 MB
    unsigned short* Pk = (unsigned short*)(ws + 8388608);     // 2 MB packed em+pad

    empack_kernel<<<dim3(NB * LQ), 256, 0, stream>>>(em, pad, Pk);
    proj_all<<<dim3(32, 8, 3), 256, 0, stream>>>(q, k, w_q_w, w_k, w_v, w_q_b, Qp, Kp, Vt);
    attn_fused<<<dim3(LQ / QT, 32), 512, 0, stream>>>(Qp, Kp, Vt, Pk, b_ks, b_vs, weights, Hb);
    outproj_mfma<<<dim3(32, 8), 256, 0, stream>>>(Hb, w_h_w, w_h_b, out);
}

// Round 6
// 174.160 us; speedup vs baseline: 1.0511x; 1.0108x over previous
//
#include <hip/hip_runtime.h>
#include <math.h>

#define NB 4
#define LQ 512
#define LK 512
#define DM 512
#define NH 8
#define DQ 64
#define NL 8
#define QT 32          // q-rows per attn block
#define PSTR 520       // Ps row stride in shorts (pad vs 512; 1040 B = 16B-aligned)

typedef short bf16x8 __attribute__((ext_vector_type(8)));
typedef float f32x4 __attribute__((ext_vector_type(4)));

__device__ __forceinline__ unsigned short f2bf(float x) {
    unsigned u = __float_as_uint(x);
    u += 0x7fff + ((u >> 16) & 1);          // RNE
    return (unsigned short)(u >> 16);
}
__device__ __forceinline__ float bf2f(unsigned x) {
    return __uint_as_float(x << 16);
}
// async global->LDS, 16B/lane; LDS dest = wave-uniform base + lane*16
__device__ __forceinline__ void gld16(const void* g, void* l) {
    __builtin_amdgcn_global_load_lds(
        (const __attribute__((address_space(1))) void*)g,
        (__attribute__((address_space(3))) void*)l, 16, 0, 0);
}

// ---------------------------------------------------------------------------
// prep: fp32->bf16 conversion of q,k,w_q,w_k,w_v,w_h (y=0..5) + em/pad 9-bit
// pack (y=6).  Pure memory-bound, fully coalesced.
// ---------------------------------------------------------------------------
__global__ __launch_bounds__(256) void prep_kernel(
        const float* __restrict__ q,  const float* __restrict__ k,
        const float* __restrict__ wq, const float* __restrict__ wk,
        const float* __restrict__ wv, const float* __restrict__ wh,
        const float* __restrict__ em, const float* __restrict__ pad,
        unsigned short* __restrict__ qb,  unsigned short* __restrict__ kb,
        unsigned short* __restrict__ wqb, unsigned short* __restrict__ wkb,
        unsigned short* __restrict__ wvb, unsigned short* __restrict__ whb,
        unsigned short* __restrict__ Pk) {
    const int tid = threadIdx.x;
    const int y = blockIdx.y;
    if (y < 6) {
        const float* s; unsigned short* d; int n;
        switch (y) {
            case 0: s = q;  d = qb;  n = NB * LQ * DM; break;
            case 1: s = k;  d = kb;  n = NB * LK * DM; break;
            case 2: s = wq; d = wqb; n = DM * DM; break;
            case 3: s = wk; d = wkb; n = DM * DM; break;
            case 4: s = wv; d = wvb; n = DM * DM; break;
            default: s = wh; d = whb; n = DM * DM; break;
        }
        const int i = blockIdx.x * 256 + tid;
        if (i * 8 >= n) return;
        const float4* sv = (const float4*)s;
        const float4 a = sv[2 * (size_t)i], b = sv[2 * (size_t)i + 1];
        uint4 o;
        o.x = (unsigned)f2bf(a.x) | ((unsigned)f2bf(a.y) << 16);
        o.y = (unsigned)f2bf(a.z) | ((unsigned)f2bf(a.w) << 16);
        o.z = (unsigned)f2bf(b.x) | ((unsigned)f2bf(b.y) << 16);
        o.w = (unsigned)f2bf(b.z) | ((unsigned)f2bf(b.w) << 16);
        *(uint4*)(d + (size_t)i * 8) = o;
    } else {
        if (blockIdx.x >= 512) return;
        const int row = blockIdx.x * 4 + (tid >> 6);      // bq row
        const int k0 = (tid & 63) * 8;
        const float* eb = em + ((size_t)row * LK + k0) * NL;
        const float4 pv0 = *(const float4*)(pad + (size_t)row * LK + k0);
        const float4 pv1 = *(const float4*)(pad + (size_t)row * LK + k0 + 4);
        const float pv[8] = {pv0.x, pv0.y, pv0.z, pv0.w, pv1.x, pv1.y, pv1.z, pv1.w};
        unsigned short outv[8];
#pragma unroll
        for (int kk = 0; kk < 8; ++kk) {
            const float4 v0 = *(const float4*)(eb + kk * 8);
            const float4 v1 = *(const float4*)(eb + kk * 8 + 4);
            unsigned b_ = 0;
            b_ |= (v0.x != 0.f) << 0; b_ |= (v0.y != 0.f) << 1;
            b_ |= (v0.z != 0.f) << 2; b_ |= (v0.w != 0.f) << 3;
            b_ |= (v1.x != 0.f) << 4; b_ |= (v1.y != 0.f) << 5;
            b_ |= (v1.z != 0.f) << 6; b_ |= (v1.w != 0.f) << 7;
            b_ |= (pv[kk] != 0.f) << 8;
            outv[kk] = (unsigned short)b_;
        }
        uint4 o;
        o.x = (unsigned)outv[0] | ((unsigned)outv[1] << 16);
        o.y = (unsigned)outv[2] | ((unsigned)outv[3] << 16);
        o.z = (unsigned)outv[4] | ((unsigned)outv[5] << 16);
        o.w = (unsigned)outv[6] | ((unsigned)outv[7] << 16);
        *(uint4*)(Pk + (size_t)row * LK + k0) = o;
    }
}

// ---------------------------------------------------------------------------
// MFMA GEMM core (round-3, pure bf16 gld16 staging): C(64x64) += A*B^T, BK=32
// ---------------------------------------------------------------------------
__device__ __forceinline__ void gemm64core(const unsigned short* __restrict__ Ag, int lda,
                                           const unsigned short* __restrict__ Bg, int ldb,
                                           int K, short* As, short* Bs,
                                           f32x4 (&acc)[2][2]) {
    const int tid = threadIdx.x;
    const int wave = tid >> 6, lane = tid & 63;
    const int quad = lane >> 4, l16 = lane & 15;
    const int wr = wave >> 1, wc = wave & 1;
    for (int k0 = 0; k0 < K; k0 += 32) {
        __syncthreads();
        gld16(Ag + (size_t)(tid >> 2) * lda + k0 + (tid & 3) * 8, (char*)As + wave * 1024);
        gld16(Bg + (size_t)(tid >> 2) * ldb + k0 + (tid & 3) * 8, (char*)Bs + wave * 1024);
        __syncthreads();
        bf16x8 af[2], bf[2];
#pragma unroll
        for (int i = 0; i < 2; ++i)
            af[i] = *(const bf16x8*)&As[(wr * 32 + i * 16 + l16) * 32 + quad * 8];
#pragma unroll
        for (int j = 0; j < 2; ++j)
            bf[j] = *(const bf16x8*)&Bs[(wc * 32 + j * 16 + l16) * 32 + quad * 8];
#pragma unroll
        for (int i = 0; i < 2; ++i)
#pragma unroll
            for (int j = 0; j < 2; ++j)
                acc[i][j] = __builtin_amdgcn_mfma_f32_16x16x32_bf16(af[i], bf[j], acc[i][j], 0, 0, 0);
    }
}

// ---------------------------------------------------------------------------
// Input projections, all-bf16 staging.  z: 0=Q, 1=K, 2=V-transposed.
// ---------------------------------------------------------------------------
__global__ __launch_bounds__(256) void proj_all(const unsigned short* __restrict__ qb,
                                                const unsigned short* __restrict__ kb,
                                                const unsigned short* __restrict__ wqb,
                                                const unsigned short* __restrict__ wkb,
                                                const unsigned short* __restrict__ wvb,
                                                const float* __restrict__ w_q_b,
                                                unsigned short* __restrict__ Qp,
                                                unsigned short* __restrict__ Kp,
                                                unsigned short* __restrict__ Vt) {
    __shared__ __align__(16) short As[64 * 32];
    __shared__ __align__(16) short Bs[64 * 32];
    const unsigned short* A; const unsigned short* W; const float* bias;
    unsigned short* C; int mode;
    switch (blockIdx.z) {
        case 0:  A = qb; W = wqb; bias = w_q_b;  C = Qp; mode = 0; break;
        case 1:  A = kb; W = wkb; bias = nullptr; C = Kp; mode = 0; break;
        default: A = kb; W = wvb; bias = nullptr; C = Vt; mode = 1; break;
    }
    f32x4 acc[2][2];
    const f32x4 zz = {0.f, 0.f, 0.f, 0.f};
#pragma unroll
    for (int i = 0; i < 2; ++i)
#pragma unroll
        for (int j = 0; j < 2; ++j) acc[i][j] = zz;
    const int m0 = blockIdx.x * 64, n0 = blockIdx.y * 64;
    gemm64core(A + (size_t)m0 * DM, DM, W + (size_t)n0 * DM, DM, DM, As, Bs, acc);
    const int tid = threadIdx.x, wave = tid >> 6, lane = tid & 63;
    const int quad = lane >> 4, l16 = lane & 15;
    const int wr = wave >> 1, wc = wave & 1;
#pragma unroll
    for (int i = 0; i < 2; ++i)
#pragma unroll
        for (int r = 0; r < 4; ++r) {
            const int gm = m0 + wr * 32 + i * 16 + quad * 4 + r;
#pragma unroll
            for (int j = 0; j < 2; ++j) {
                const int gn = n0 + wc * 32 + j * 16 + l16;
                float v = acc[i][j][r];
                if (bias) v += bias[gn];
                if (mode == 0) C[(size_t)gm * DM + gn] = f2bf(v);
                else C[(size_t)(gm >> 9) * (DM * LK) + (size_t)gn * LK + (gm & 511)] = f2bf(v);
            }
        }
}

// ---------------------------------------------------------------------------
// Fused attention per (z = h*4+b, 32-q-row tile).  512 thr = 8 waves.
// Online-softmax: ONE reduction barrier.  t-loop uses b128 loads.
// ---------------------------------------------------------------------------
__global__ __launch_bounds__(512, 4) void attn_fused(
        const unsigned short* __restrict__ Qp,
        const unsigned short* __restrict__ Kp,
        const unsigned short* __restrict__ Vt,
        const unsigned short* __restrict__ Pk,
        const float* __restrict__ b_ks,
        const float* __restrict__ b_vs,
        float* __restrict__ weights,
        unsigned short* __restrict__ Hb) {
    __shared__ __align__(16) short Qs[QT * 64];       // 4 KB
    __shared__ __align__(16) short Kc[128 * 64];      // 16 KB  K/V chunk
    __shared__ __align__(16) short Ps[QT * PSTR];     // 32.5 KB attn bf16
    __shared__ float svS[QT * NL];
    __shared__ float tS[QT * NL];
    __shared__ float redA[QT * 8];                    // per-wave-group max
    __shared__ float redB[QT * 8];                    // per-wave-group sum

    const int tid = threadIdx.x, wave = tid >> 6, lane = tid & 63;
    const int quad = lane >> 4, l16 = lane & 15;
    const int q0 = blockIdx.x * QT;
    const int z = blockIdx.y, h = z >> 2, b = z & 3;

    // ---- stage Q tile ----
    if (tid < 256) {
        const int row = tid >> 3, off = (tid & 7) * 8;
        gld16(Qp + (size_t)(b * LQ + q0 + row) * DM + h * DQ + off,
              (char*)Qs + wave * 1024);
    }

    // ---- QK^T: S[32 x 512] in 4 chunks of 128 k-rows ----
    f32x4 acc[4][2];
    const f32x4 zz = {0.f, 0.f, 0.f, 0.f};
#pragma unroll
    for (int c = 0; c < 4; ++c) { acc[c][0] = zz; acc[c][1] = zz; }

    for (int c = 0; c < 4; ++c) {
#pragma unroll
        for (int it = 0; it < 2; ++it) {
            const int e = it * 512 + tid;
            const int kr = c * 128 + (e >> 3), off = (e & 7) * 8;
            gld16(Kp + (size_t)(b * LK + kr) * DM + h * DQ + off,
                  (char*)Kc + it * 8192 + wave * 1024);
        }
        __syncthreads();
#pragma unroll
        for (int kd = 0; kd < 64; kd += 32) {
            const bf16x8 bfv = *(const bf16x8*)&Kc[(wave * 16 + l16) * 64 + kd + quad * 8];
#pragma unroll
            for (int i = 0; i < 2; ++i) {
                const bf16x8 afv = *(const bf16x8*)&Qs[(i * 16 + l16) * 64 + kd + quad * 8];
                acc[c][i] = __builtin_amdgcn_mfma_f32_16x16x32_bf16(afv, bfv, acc[c][i], 0, 0, 0);
            }
        }
        if (c == 0 && tid < 256) {
            const int row = tid >> 3, l = tid & 7;
            float s = 0.f;
#pragma unroll
            for (int d = 0; d < DQ; ++d)
                s = fmaf(bf2f((unsigned short)Qs[row * 64 + d]), b_ks[l * DQ + d], s);
            svS[row * 8 + l] = s;
        }
        __syncthreads();
    }

    // ---- prefetch V chunk 0 into Kc (drains at the pass-B barrier) ----
#pragma unroll
    for (int it = 0; it < 2; ++it) {
        const int e = it * 512 + tid;
        const int dd = e >> 4, off = (e & 15) * 8;
        gld16(Vt + (size_t)(b * DM + h * DQ + dd) * LK + off,
              (char*)Kc + it * 8192 + wave * 1024);
    }

    // ---- pass A: rel + mask + weights write + per-wave-group (max,sum) ----
#pragma unroll
    for (int i = 0; i < 2; ++i)
#pragma unroll
        for (int r = 0; r < 4; ++r) {
            const int row = i * 16 + quad * 4 + r;
            const int gq = q0 + row;
            const f32x4 sv0 = *(const f32x4*)&svS[row * 8];
            const f32x4 sv1 = *(const f32x4*)&svS[row * 8 + 4];
            const unsigned short* prow = Pk + (size_t)(b * LQ + gq) * LK;
            float* wrow = weights + ((size_t)z * LQ + gq) * LK;
            float pm = -__builtin_inff();
#pragma unroll
            for (int c = 0; c < 4; ++c) {
                const int col = c * 128 + wave * 16 + l16;
                const unsigned w_ = prow[col];
                float rel = 0.f;
                rel = fmaf((float)((w_ >> 0) & 1), sv0[0], rel);
                rel = fmaf((float)((w_ >> 1) & 1), sv0[1], rel);
                rel = fmaf((float)((w_ >> 2) & 1), sv0[2], rel);
                rel = fmaf((float)((w_ >> 3) & 1), sv0[3], rel);
                rel = fmaf((float)((w_ >> 4) & 1), sv1[0], rel);
                rel = fmaf((float)((w_ >> 5) & 1), sv1[1], rel);
                rel = fmaf((float)((w_ >> 6) & 1), sv1[2], rel);
                rel = fmaf((float)((w_ >> 7) & 1), sv1[3], rel);
                const float wv = (acc[c][i][r] + rel) * 0.125f;
                wrow[col] = wv;                               // pre-mask weights
                const float m = ((w_ & 0x1FFu) == 0x100u) ? -__builtin_inff() : wv;
                acc[c][i][r] = m;
                pm = fmaxf(pm, m);
            }
#pragma unroll
            for (int o = 1; o < 16; o <<= 1) pm = fmaxf(pm, __shfl_xor(pm, o, 64));
            float ps = 0.f;
#pragma unroll
            for (int c = 0; c < 4; ++c) {
                const float e = __expf(acc[c][i][r] - pm);    // masked -> 0
                acc[c][i][r] = e;
                ps += e;
            }
#pragma unroll
            for (int o = 1; o < 16; o <<= 1) ps += __shfl_xor(ps, o, 64);
            if (l16 == 0) { redA[row * 8 + wave] = pm; redB[row * 8 + wave] = ps; }
        }
    __syncthreads();

    // ---- pass B: online merge across 8 wave-groups, normalize, write Ps ----
#pragma unroll
    for (int i = 0; i < 2; ++i)
#pragma unroll
        for (int r = 0; r < 4; ++r) {
            const int row = i * 16 + quad * 4 + r;
            const f32x4 pa = *(const f32x4*)&redA[row * 8];
            const f32x4 pb = *(const f32x4*)&redA[row * 8 + 4];
            const f32x4 sa = *(const f32x4*)&redB[row * 8];
            const f32x4 sb = *(const f32x4*)&redB[row * 8 + 4];
            const float M = fmaxf(fmaxf(fmaxf(pa[0], pa[1]), fmaxf(pa[2], pa[3])),
                                  fmaxf(fmaxf(pb[0], pb[1]), fmaxf(pb[2], pb[3])));
            const float S = sa[0] * __expf(pa[0] - M) + sa[1] * __expf(pa[1] - M)
                          + sa[2] * __expf(pa[2] - M) + sa[3] * __expf(pa[3] - M)
                          + sb[0] * __expf(pb[0] - M) + sb[1] * __expf(pb[1] - M)
                          + sb[2] * __expf(pb[2] - M) + sb[3] * __expf(pb[3] - M);
            const float own = redA[row * 8 + wave];
            const float alpha = __expf(own - M) / S;
#pragma unroll
            for (int c = 0; c < 4; ++c) {
                const int col = c * 128 + wave * 16 + l16;
                Ps[row * PSTR + col] = (short)f2bf(acc[c][i][r] * alpha);
            }
        }
    __syncthreads();   // Ps visible; V chunk 0 resident

    // ---- t[q][l] = sum_k attn * em_bit_l, b128 loads (broadcast-friendly) --
    {
        const int row = tid >> 4, l = (tid >> 1) & 7, half = tid & 1;
        const uint4* pw = (const uint4*)(Pk + (size_t)(b * LQ + q0 + row) * LK + half * 256);
        const uint4* aw = (const uint4*)&Ps[row * PSTR + half * 256];
        float tv = 0.f;
#pragma unroll 4
        for (int kk = 0; kk < 32; ++kk) {
            const uint4 wb = pw[kk];
            const uint4 av = aw[kk];
            const unsigned w4[4] = {wb.x, wb.y, wb.z, wb.w};
            const unsigned a4[4] = {av.x, av.y, av.z, av.w};
#pragma unroll
            for (int u = 0; u < 4; ++u) {
                tv += ((w4[u] >> l) & 1)        ? bf2f(a4[u] & 0xffffu) : 0.f;
                tv += ((w4[u] >> (16 + l)) & 1) ? bf2f(a4[u] >> 16)     : 0.f;
            }
        }
        tv += __shfl_xor(tv, 1, 64);
        if (half == 0) tS[row * 8 + l] = tv;
    }

    // ---- PV: O[32 x 64] = attn @ V, V streamed in 4 chunks of 128 k ----
    f32x4 oacc = zz;
    const int mi = wave & 1, ni = wave >> 1;
    for (int vc = 0; vc < 4; ++vc) {
        if (vc > 0) {
            __syncthreads();
#pragma unroll
            for (int it = 0; it < 2; ++it) {
                const int e = it * 512 + tid;
                const int dd = e >> 4, off = (e & 15) * 8;
                gld16(Vt + (size_t)(b * DM + h * DQ + dd) * LK + vc * 128 + off,
                      (char*)Kc + it * 8192 + wave * 1024);
            }
            __syncthreads();
        }
#pragma unroll
        for (int kd = 0; kd < 128; kd += 32) {
            const bf16x8 afv = *(const bf16x8*)&Ps[(mi * 16 + l16) * PSTR + vc * 128 + kd + quad * 8];
            const bf16x8 bfv = *(const bf16x8*)&Kc[(ni * 16 + l16) * 128 + kd + quad * 8];
            oacc = __builtin_amdgcn_mfma_f32_16x16x32_bf16(afv, bfv, oacc, 0, 0, 0);
        }
    }

    // ---- output epilogue: + qvr, store Hb bf16 ----
    const int gd = ni * 16 + l16;
    float bvv[NL];
#pragma unroll
    for (int l = 0; l < NL; ++l) bvv[l] = b_vs[l * DQ + gd];
#pragma unroll
    for (int r = 0; r < 4; ++r) {
        const int row = mi * 16 + quad * 4 + r;
        const float* tp = &tS[row * 8];
        float o = oacc[r];
#pragma unroll
        for (int l = 0; l < NL; ++l) o = fmaf(tp[l], bvv[l], o);
        Hb[(size_t)(b * LQ + q0 + row) * DM + h * DQ + gd] = f2bf(o);
    }
}

// ---------------------------------------------------------------------------
// Output projection: Hb(bf16) @ whb(bf16)^T + bias, fp32 store.  Grid (32,8).
// ---------------------------------------------------------------------------
__global__ __launch_bounds__(256) void outproj_mfma(const unsigned short* __restrict__ Hb,
                                                    const unsigned short* __restrict__ whb,
                                                    const float* __restrict__ bias,
                                                    float* __restrict__ C) {
    __shared__ __align__(16) short As[64 * 32];
    __shared__ __align__(16) short Bs[64 * 32];
    f32x4 acc[2][2];
    const f32x4 zz = {0.f, 0.f, 0.f, 0.f};
#pragma unroll
    for (int i = 0; i < 2; ++i)
#pragma unroll
        for (int j = 0; j < 2; ++j) acc[i][j] = zz;
    const int m0 = blockIdx.x * 64, n0 = blockIdx.y * 64;
    gemm64core(Hb + (size_t)m0 * DM, DM, whb + (size_t)n0 * DM, DM, DM, As, Bs, acc);
    const int tid = threadIdx.x, wave = tid >> 6, lane = tid & 63;
    const int quad = lane >> 4, l16 = lane & 15;
    const int wr = wave >> 1, wc = wave & 1;
#pragma unroll
    for (int i = 0; i < 2; ++i)
#pragma unroll
        for (int r = 0; r < 4; ++r) {
            const int gm = m0 + wr * 32 + i * 16 + quad * 4 + r;
#pragma unroll
            for (int j = 0; j < 2; ++j) {
                const int gn = n0 + wc * 32 + j * 16 + l16;
                C[(size_t)gm * DM + gn] = acc[i][j][r] + bias[gn];
            }
        }
}

// ---------------------------------------------------------------------------
extern "C" void kernel_launch(void* const* d_in, const int* in_sizes, int n_in,
                              void* d_out, int out_size, void* d_ws, size_t ws_size,
                              hipStream_t stream) {
    const float* q     = (const float*)d_in[0];
    const float* k     = (const float*)d_in[1];
    const float* em    = (const float*)d_in[2];
    const float* pad   = (const float*)d_in[3];
    const float* w_q_w = (const float*)d_in[4];
    const float* w_q_b = (const float*)d_in[5];
    const float* w_k   = (const float*)d_in[6];
    const float* w_v   = (const float*)d_in[7];
    const float* w_h_w = (const float*)d_in[8];
    const float* w_h_b = (const float*)d_in[9];
    const float* b_ks  = (const float*)d_in[10];
    const float* b_vs  = (const float*)d_in[11];

    float* out     = (float*)d_out;                       // (B, LQ, DM) fp32
    float* weights = out + (size_t)NB * LQ * DM;          // (H*B, LQ, LK) fp32

    char* ws = (char*)d_ws;
    unsigned short* qb  = (unsigned short*)(ws + 0);          // 2 MB
    unsigned short* kb  = (unsigned short*)(ws + 2097152);    // 2 MB
    unsigned short* wqb = (unsigned short*)(ws + 4194304);    // 512 KB
    unsigned short* wkb = (unsigned short*)(ws + 4718592);
    unsigned short* wvb = (unsigned short*)(ws + 5242880);
    unsigned short* whb = (unsigned short*)(ws + 5767168);
    unsigned short* Qp  = (unsigned short*)(ws + 6291456);    // 2 MB
    unsigned short* Kp  = (unsigned short*)(ws + 8388608);    // 2 MB
    unsigned short* Vt  = (unsigned short*)(ws + 10485760);   // 2 MB
    unsigned short* Hb  = (unsigned short*)(ws + 12582912);   // 2 MB
    unsigned short* Pk  = (unsigned short*)(ws + 14680064);   // 2 MB

    prep_kernel<<<dim3(1024, 7), 256, 0, stream>>>(q, k, w_q_w, w_k, w_v, w_h_w,
                                                   em, pad, qb, kb, wqb, wkb, wvb, whb, Pk);
    proj_all<<<dim3(32, 8, 3), 256, 0, stream>>>(qb, kb, wqb, wkb, wvb, w_q_b, Qp, Kp, Vt);
    attn_fused<<<dim3(LQ / QT, 32), 512, 0, stream>>>(Qp, Kp, Vt, Pk, b_ks, b_vs, weights, Hb);
    outproj_mfma<<<dim3(32, 8), 256, 0, stream>>>(Hb, whb, w_h_b, out);
}

// Round 7
// 169.769 us; speedup vs baseline: 1.0783x; 1.0259x over previous
//
#include <hip/hip_runtime.h>
#include <math.h>

#define NB 4
#define LQ 512
#define LK 512
#define DM 512
#define NH 8
#define DQ 64
#define NL 8
#define QT 32          // q-rows per attn block
#define PSTR 520       // Ps row stride in shorts (260 dwords % 32 = 4 -> 2-way max)

typedef short bf16x8 __attribute__((ext_vector_type(8)));
typedef float f32x4 __attribute__((ext_vector_type(4)));

__device__ __forceinline__ unsigned short f2bf(float x) {
    unsigned u = __float_as_uint(x);
    u += 0x7fff + ((u >> 16) & 1);          // RNE
    return (unsigned short)(u >> 16);
}
__device__ __forceinline__ float bf2f(unsigned x) {
    return __uint_as_float(x << 16);
}
// async global->LDS, 16B/lane; LDS dest = wave-uniform base + lane*16
__device__ __forceinline__ void gld16(const void* g, void* l) {
    __builtin_amdgcn_global_load_lds(
        (const __attribute__((address_space(1))) void*)g,
        (__attribute__((address_space(3))) void*)l, 16, 0, 0);
}

// ---------------------------------------------------------------------------
// prep: fp32->bf16 conversion of q,k,w_q,w_k,w_v,w_h (y=0..5) + em/pad 9-bit
// pack (y=6).  Pure memory-bound, fully coalesced.
// ---------------------------------------------------------------------------
__global__ __launch_bounds__(256) void prep_kernel(
        const float* __restrict__ q,  const float* __restrict__ k,
        const float* __restrict__ wq, const float* __restrict__ wk,
        const float* __restrict__ wv, const float* __restrict__ wh,
        const float* __restrict__ em, const float* __restrict__ pad,
        unsigned short* __restrict__ qb,  unsigned short* __restrict__ kb,
        unsigned short* __restrict__ wqb, unsigned short* __restrict__ wkb,
        unsigned short* __restrict__ wvb, unsigned short* __restrict__ whb,
        unsigned short* __restrict__ Pk) {
    const int tid = threadIdx.x;
    const int y = blockIdx.y;
    if (y < 6) {
        const float* s; unsigned short* d; int n;
        switch (y) {
            case 0: s = q;  d = qb;  n = NB * LQ * DM; break;
            case 1: s = k;  d = kb;  n = NB * LK * DM; break;
            case 2: s = wq; d = wqb; n = DM * DM; break;
            case 3: s = wk; d = wkb; n = DM * DM; break;
            case 4: s = wv; d = wvb; n = DM * DM; break;
            default: s = wh; d = whb; n = DM * DM; break;
        }
        const int i = blockIdx.x * 256 + tid;
        if (i * 8 >= n) return;
        const float4* sv = (const float4*)s;
        const float4 a = sv[2 * (size_t)i], b = sv[2 * (size_t)i + 1];
        uint4 o;
        o.x = (unsigned)f2bf(a.x) | ((unsigned)f2bf(a.y) << 16);
        o.y = (unsigned)f2bf(a.z) | ((unsigned)f2bf(a.w) << 16);
        o.z = (unsigned)f2bf(b.x) | ((unsigned)f2bf(b.y) << 16);
        o.w = (unsigned)f2bf(b.z) | ((unsigned)f2bf(b.w) << 16);
        *(uint4*)(d + (size_t)i * 8) = o;
    } else {
        if (blockIdx.x >= 512) return;
        const int row = blockIdx.x * 4 + (tid >> 6);      // bq row
        const int k0 = (tid & 63) * 8;
        const float* eb = em + ((size_t)row * LK + k0) * NL;
        const float4 pv0 = *(const float4*)(pad + (size_t)row * LK + k0);
        const float4 pv1 = *(const float4*)(pad + (size_t)row * LK + k0 + 4);
        const float pv[8] = {pv0.x, pv0.y, pv0.z, pv0.w, pv1.x, pv1.y, pv1.z, pv1.w};
        unsigned short outv[8];
#pragma unroll
        for (int kk = 0; kk < 8; ++kk) {
            const float4 v0 = *(const float4*)(eb + kk * 8);
            const float4 v1 = *(const float4*)(eb + kk * 8 + 4);
            unsigned b_ = 0;
            b_ |= (v0.x != 0.f) << 0; b_ |= (v0.y != 0.f) << 1;
            b_ |= (v0.z != 0.f) << 2; b_ |= (v0.w != 0.f) << 3;
            b_ |= (v1.x != 0.f) << 4; b_ |= (v1.y != 0.f) << 5;
            b_ |= (v1.z != 0.f) << 6; b_ |= (v1.w != 0.f) << 7;
            b_ |= (pv[kk] != 0.f) << 8;
            outv[kk] = (unsigned short)b_;
        }
        uint4 o;
        o.x = (unsigned)outv[0] | ((unsigned)outv[1] << 16);
        o.y = (unsigned)outv[2] | ((unsigned)outv[3] << 16);
        o.z = (unsigned)outv[4] | ((unsigned)outv[5] << 16);
        o.w = (unsigned)outv[6] | ((unsigned)outv[7] << 16);
        *(uint4*)(Pk + (size_t)row * LK + k0) = o;
    }
}

// ---------------------------------------------------------------------------
// MFMA GEMM core: C(64x64) += A*B^T, BK=32.  LDS stride 32 shorts = 16 dwords
// -> 2-way max, no swizzle needed.
// ---------------------------------------------------------------------------
__device__ __forceinline__ void gemm64core(const unsigned short* __restrict__ Ag, int lda,
                                           const unsigned short* __restrict__ Bg, int ldb,
                                           int K, short* As, short* Bs,
                                           f32x4 (&acc)[2][2]) {
    const int tid = threadIdx.x;
    const int wave = tid >> 6, lane = tid & 63;
    const int quad = lane >> 4, l16 = lane & 15;
    const int wr = wave >> 1, wc = wave & 1;
    for (int k0 = 0; k0 < K; k0 += 32) {
        __syncthreads();
        gld16(Ag + (size_t)(tid >> 2) * lda + k0 + (tid & 3) * 8, (char*)As + wave * 1024);
        gld16(Bg + (size_t)(tid >> 2) * ldb + k0 + (tid & 3) * 8, (char*)Bs + wave * 1024);
        __syncthreads();
        bf16x8 af[2], bf[2];
#pragma unroll
        for (int i = 0; i < 2; ++i)
            af[i] = *(const bf16x8*)&As[(wr * 32 + i * 16 + l16) * 32 + quad * 8];
#pragma unroll
        for (int j = 0; j < 2; ++j)
            bf[j] = *(const bf16x8*)&Bs[(wc * 32 + j * 16 + l16) * 32 + quad * 8];
#pragma unroll
        for (int i = 0; i < 2; ++i)
#pragma unroll
            for (int j = 0; j < 2; ++j)
                acc[i][j] = __builtin_amdgcn_mfma_f32_16x16x32_bf16(af[i], bf[j], acc[i][j], 0, 0, 0);
    }
}

// ---------------------------------------------------------------------------
// Input projections, all-bf16 staging.  z: 0=Q, 1=K, 2=V-transposed.
// ---------------------------------------------------------------------------
__global__ __launch_bounds__(256) void proj_all(const unsigned short* __restrict__ qb,
                                                const unsigned short* __restrict__ kb,
                                                const unsigned short* __restrict__ wqb,
                                                const unsigned short* __restrict__ wkb,
                                                const unsigned short* __restrict__ wvb,
                                                const float* __restrict__ w_q_b,
                                                unsigned short* __restrict__ Qp,
                                                unsigned short* __restrict__ Kp,
                                                unsigned short* __restrict__ Vt) {
    __shared__ __align__(16) short As[64 * 32];
    __shared__ __align__(16) short Bs[64 * 32];
    const unsigned short* A; const unsigned short* W; const float* bias;
    unsigned short* C; int mode;
    switch (blockIdx.z) {
        case 0:  A = qb; W = wqb; bias = w_q_b;  C = Qp; mode = 0; break;
        case 1:  A = kb; W = wkb; bias = nullptr; C = Kp; mode = 0; break;
        default: A = kb; W = wvb; bias = nullptr; C = Vt; mode = 1; break;
    }
    f32x4 acc[2][2];
    const f32x4 zz = {0.f, 0.f, 0.f, 0.f};
#pragma unroll
    for (int i = 0; i < 2; ++i)
#pragma unroll
        for (int j = 0; j < 2; ++j) acc[i][j] = zz;
    const int m0 = blockIdx.x * 64, n0 = blockIdx.y * 64;
    gemm64core(A + (size_t)m0 * DM, DM, W + (size_t)n0 * DM, DM, DM, As, Bs, acc);
    const int tid = threadIdx.x, wave = tid >> 6, lane = tid & 63;
    const int quad = lane >> 4, l16 = lane & 15;
    const int wr = wave >> 1, wc = wave & 1;
#pragma unroll
    for (int i = 0; i < 2; ++i)
#pragma unroll
        for (int r = 0; r < 4; ++r) {
            const int gm = m0 + wr * 32 + i * 16 + quad * 4 + r;
#pragma unroll
            for (int j = 0; j < 2; ++j) {
                const int gn = n0 + wc * 32 + j * 16 + l16;
                float v = acc[i][j][r];
                if (bias) v += bias[gn];
                if (mode == 0) C[(size_t)gm * DM + gn] = f2bf(v);
                else C[(size_t)(gm >> 9) * (DM * LK) + (size_t)gn * LK + (gm & 511)] = f2bf(v);
            }
        }
}

// ---------------------------------------------------------------------------
// Fused attention per (z = h*4+b, 32-q-row tile).  512 thr = 8 waves.
// XOR-swizzled LDS tiles: row stride of Qs/Kc is 0 mod 32 banks, so logical
// chunk c of row r lives at slot c ^ (r & 7) (8-chunk rows) or c ^ (r & 15)
// (16-chunk rows) -> every ds_read_b128 is <=2-way (free) instead of 16-way.
// ---------------------------------------------------------------------------
__global__ __launch_bounds__(512, 4) void attn_fused(
        const unsigned short* __restrict__ Qp,
        const unsigned short* __restrict__ Kp,
        const unsigned short* __restrict__ Vt,
        const unsigned short* __restrict__ Pk,
        const float* __restrict__ b_ks,
        const float* __restrict__ b_vs,
        float* __restrict__ weights,
        unsigned short* __restrict__ Hb) {
    __shared__ __align__(16) short Qs[QT * 64];       // 4 KB   [q][d] swizzled
    __shared__ __align__(16) short Kc[128 * 64];      // 16 KB  K/V chunk swizzled
    __shared__ __align__(16) short Ps[QT * PSTR];     // 32.5 KB attn bf16
    __shared__ float svS[QT * NL];
    __shared__ float tS[QT * NL];
    __shared__ float redA[QT * 8];                    // per-wave-group max
    __shared__ float redB[QT * 8];                    // per-wave-group sum

    const int tid = threadIdx.x, wave = tid >> 6, lane = tid & 63;
    const int quad = lane >> 4, l16 = lane & 15;
    const int q0 = blockIdx.x * QT;
    const int z = blockIdx.y, h = z >> 2, b = z & 3;

    // ---- stage Q tile (swizzled: slot chunk p holds global chunk p^(row&7))
    if (tid < 256) {
        const int row = tid >> 3, ch = tid & 7;
        gld16(Qp + (size_t)(b * LQ + q0 + row) * DM + h * DQ + ((ch ^ (row & 7)) * 8),
              (char*)Qs + wave * 1024);
    }

    // ---- QK^T: S[32 x 512] in 4 chunks of 128 k-rows ----
    f32x4 acc[4][2];
    const f32x4 zz = {0.f, 0.f, 0.f, 0.f};
#pragma unroll
    for (int c = 0; c < 4; ++c) { acc[c][0] = zz; acc[c][1] = zz; }

    for (int c = 0; c < 4; ++c) {
#pragma unroll
        for (int it = 0; it < 2; ++it) {
            const int e = it * 512 + tid;
            const int kr = e >> 3, ch = e & 7;
            gld16(Kp + (size_t)(b * LK + c * 128 + kr) * DM + h * DQ + ((ch ^ (kr & 7)) * 8),
                  (char*)Kc + it * 8192 + wave * 1024);
        }
        __syncthreads();
#pragma unroll
        for (int kd = 0; kd < 64; kd += 32) {
            const int krow = wave * 16 + l16;
            const int kch = ((kd >> 3) + quad) ^ (krow & 7);
            const bf16x8 bfv = *(const bf16x8*)&Kc[krow * 64 + kch * 8];
#pragma unroll
            for (int i = 0; i < 2; ++i) {
                const int qrow = i * 16 + l16;
                const int qch = ((kd >> 3) + quad) ^ (qrow & 7);
                const bf16x8 afv = *(const bf16x8*)&Qs[qrow * 64 + qch * 8];
                acc[c][i] = __builtin_amdgcn_mfma_f32_16x16x32_bf16(afv, bfv, acc[c][i], 0, 0, 0);
            }
        }
        if (c == 0 && tid < 256) {
            // sv[row][l] = sum_d Q[row][d]*b_ks[l][d]; un-swizzle d: chunk of d
            const int row = tid >> 3, l = tid & 7;
            float s = 0.f;
#pragma unroll
            for (int d = 0; d < DQ; ++d) {
                const int ds = ((d >> 3) ^ (row & 7)) * 8 + (d & 7);
                s = fmaf(bf2f((unsigned short)Qs[row * 64 + ds]), b_ks[l * DQ + d], s);
            }
            svS[row * 8 + l] = s;
        }
        __syncthreads();
    }

    // ---- prefetch V chunk 0 into Kc (16-chunk rows, swizzle by row&15) ----
#pragma unroll
    for (int it = 0; it < 2; ++it) {
        const int e = it * 512 + tid;
        const int dd = e >> 4, ch = e & 15;
        gld16(Vt + (size_t)(b * DM + h * DQ + dd) * LK + ((ch ^ (dd & 15)) * 8),
              (char*)Kc + it * 8192 + wave * 1024);
    }

    // ---- pass A: rel + mask + weights write + per-wave-group (max,sum) ----
#pragma unroll
    for (int i = 0; i < 2; ++i)
#pragma unroll
        for (int r = 0; r < 4; ++r) {
            const int row = i * 16 + quad * 4 + r;
            const int gq = q0 + row;
            const f32x4 sv0 = *(const f32x4*)&svS[row * 8];
            const f32x4 sv1 = *(const f32x4*)&svS[row * 8 + 4];
            const unsigned short* prow = Pk + (size_t)(b * LQ + gq) * LK;
            float* wrow = weights + ((size_t)z * LQ + gq) * LK;
            float pm = -__builtin_inff();
#pragma unroll
            for (int c = 0; c < 4; ++c) {
                const int col = c * 128 + wave * 16 + l16;
                const unsigned w_ = prow[col];
                float rel = 0.f;
                rel = fmaf((float)((w_ >> 0) & 1), sv0[0], rel);
                rel = fmaf((float)((w_ >> 1) & 1), sv0[1], rel);
                rel = fmaf((float)((w_ >> 2) & 1), sv0[2], rel);
                rel = fmaf((float)((w_ >> 3) & 1), sv0[3], rel);
                rel = fmaf((float)((w_ >> 4) & 1), sv1[0], rel);
                rel = fmaf((float)((w_ >> 5) & 1), sv1[1], rel);
                rel = fmaf((float)((w_ >> 6) & 1), sv1[2], rel);
                rel = fmaf((float)((w_ >> 7) & 1), sv1[3], rel);
                const float wv = (acc[c][i][r] + rel) * 0.125f;
                wrow[col] = wv;                               // pre-mask weights
                const float m = ((w_ & 0x1FFu) == 0x100u) ? -__builtin_inff() : wv;
                acc[c][i][r] = m;
                pm = fmaxf(pm, m);
            }
#pragma unroll
            for (int o = 1; o < 16; o <<= 1) pm = fmaxf(pm, __shfl_xor(pm, o, 64));
            float ps = 0.f;
#pragma unroll
            for (int c = 0; c < 4; ++c) {
                const float e = __expf(acc[c][i][r] - pm);    // masked -> 0
                acc[c][i][r] = e;
                ps += e;
            }
#pragma unroll
            for (int o = 1; o < 16; o <<= 1) ps += __shfl_xor(ps, o, 64);
            if (l16 == 0) { redA[row * 8 + wave] = pm; redB[row * 8 + wave] = ps; }
        }
    __syncthreads();

    // ---- pass B: online merge across 8 wave-groups, normalize, write Ps ----
#pragma unroll
    for (int i = 0; i < 2; ++i)
#pragma unroll
        for (int r = 0; r < 4; ++r) {
            const int row = i * 16 + quad * 4 + r;
            const f32x4 pa = *(const f32x4*)&redA[row * 8];
            const f32x4 pb = *(const f32x4*)&redA[row * 8 + 4];
            const f32x4 sa = *(const f32x4*)&redB[row * 8];
            const f32x4 sb = *(const f32x4*)&redB[row * 8 + 4];
            const float M = fmaxf(fmaxf(fmaxf(pa[0], pa[1]), fmaxf(pa[2], pa[3])),
                                  fmaxf(fmaxf(pb[0], pb[1]), fmaxf(pb[2], pb[3])));
            const float S = sa[0] * __expf(pa[0] - M) + sa[1] * __expf(pa[1] - M)
                          + sa[2] * __expf(pa[2] - M) + sa[3] * __expf(pa[3] - M)
                          + sb[0] * __expf(pb[0] - M) + sb[1] * __expf(pb[1] - M)
                          + sb[2] * __expf(pb[2] - M) + sb[3] * __expf(pb[3] - M);
            const float own = redA[row * 8 + wave];
            const float alpha = __expf(own - M) / S;
#pragma unroll
            for (int c = 0; c < 4; ++c) {
                const int col = c * 128 + wave * 16 + l16;
                Ps[row * PSTR + col] = (short)f2bf(acc[c][i][r] * alpha);
            }
        }
    __syncthreads();   // Ps visible; V chunk 0 resident

    // ---- t[q][l] = sum_k attn * em_bit_l, b128 loads (broadcast-friendly) --
    {
        const int row = tid >> 4, l = (tid >> 1) & 7, half = tid & 1;
        const uint4* pw = (const uint4*)(Pk + (size_t)(b * LQ + q0 + row) * LK + half * 256);
        const uint4* aw = (const uint4*)&Ps[row * PSTR + half * 256];
        float tv = 0.f;
#pragma unroll 4
        for (int kk = 0; kk < 32; ++kk) {
            const uint4 wb = pw[kk];
            const uint4 av = aw[kk];
            const unsigned w4[4] = {wb.x, wb.y, wb.z, wb.w};
            const unsigned a4[4] = {av.x, av.y, av.z, av.w};
#pragma unroll
            for (int u = 0; u < 4; ++u) {
                tv += ((w4[u] >> l) & 1)        ? bf2f(a4[u] & 0xffffu) : 0.f;
                tv += ((w4[u] >> (16 + l)) & 1) ? bf2f(a4[u] >> 16)     : 0.f;
            }
        }
        tv += __shfl_xor(tv, 1, 64);
        if (half == 0) tS[row * 8 + l] = tv;
    }

    // ---- PV: O[32 x 64] = attn @ V, V streamed in 4 chunks of 128 k ----
    f32x4 oacc = zz;
    const int mi = wave & 1, ni = wave >> 1;
    for (int vc = 0; vc < 4; ++vc) {
        if (vc > 0) {
            __syncthreads();
#pragma unroll
            for (int it = 0; it < 2; ++it) {
                const int e = it * 512 + tid;
                const int dd = e >> 4, ch = e & 15;
                gld16(Vt + (size_t)(b * DM + h * DQ + dd) * LK + vc * 128 + ((ch ^ (dd & 15)) * 8),
                      (char*)Kc + it * 8192 + wave * 1024);
            }
            __syncthreads();
        }
#pragma unroll
        for (int kd = 0; kd < 128; kd += 32) {
            const int vrow = ni * 16 + l16;
            const int vch = ((kd >> 3) + quad) ^ (vrow & 15);
            const bf16x8 afv = *(const bf16x8*)&Ps[(mi * 16 + l16) * PSTR + vc * 128 + kd + quad * 8];
            const bf16x8 bfv = *(const bf16x8*)&Kc[vrow * 128 + vch * 8];
            oacc = __builtin_amdgcn_mfma_f32_16x16x32_bf16(afv, bfv, oacc, 0, 0, 0);
        }
    }

    // ---- output epilogue: + qvr, store Hb bf16 ----
    const int gd = ni * 16 + l16;
    float bvv[NL];
#pragma unroll
    for (int l = 0; l < NL; ++l) bvv[l] = b_vs[l * DQ + gd];
#pragma unroll
    for (int r = 0; r < 4; ++r) {
        const int row = mi * 16 + quad * 4 + r;
        const float* tp = &tS[row * 8];
        float o = oacc[r];
#pragma unroll
        for (int l = 0; l < NL; ++l) o = fmaf(tp[l], bvv[l], o);
        Hb[(size_t)(b * LQ + q0 + row) * DM + h * DQ + gd] = f2bf(o);
    }
}

// ---------------------------------------------------------------------------
// Output projection: Hb(bf16) @ whb(bf16)^T + bias, fp32 store.  Grid (32,8).
// ---------------------------------------------------------------------------
__global__ __launch_bounds__(256) void outproj_mfma(const unsigned short* __restrict__ Hb,
                                                    const unsigned short* __restrict__ whb,
                                                    const float* __restrict__ bias,
                                                    float* __restrict__ C) {
    __shared__ __align__(16) short As[64 * 32];
    __shared__ __align__(16) short Bs[64 * 32];
    f32x4 acc[2][2];
    const f32x4 zz = {0.f, 0.f, 0.f, 0.f};
#pragma unroll
    for (int i = 0; i < 2; ++i)
#pragma unroll
        for (int j = 0; j < 2; ++j) acc[i][j] = zz;
    const int m0 = blockIdx.x * 64, n0 = blockIdx.y * 64;
    gemm64core(Hb + (size_t)m0 * DM, DM, whb + (size_t)n0 * DM, DM, DM, As, Bs, acc);
    const int tid = threadIdx.x, wave = tid >> 6, lane = tid & 63;
    const int quad = lane >> 4, l16 = lane & 15;
    const int wr = wave >> 1, wc = wave & 1;
#pragma unroll
    for (int i = 0; i < 2; ++i)
#pragma unroll
        for (int r = 0; r < 4; ++r) {
            const int gm = m0 + wr * 32 + i * 16 + quad * 4 + r;
#pragma unroll
            for (int j = 0; j < 2; ++j) {
                const int gn = n0 + wc * 32 + j * 16 + l16;
                C[(size_t)gm * DM + gn] = acc[i][j][r] + bias[gn];
            }
        }
}

// ---------------------------------------------------------------------------
extern "C" void kernel_launch(void* const* d_in, const int* in_sizes, int n_in,
                              void* d_out, int out_size, void* d_ws, size_t ws_size,
                              hipStream_t stream) {
    const float* q     = (const float*)d_in[0];
    const float* k     = (const float*)d_in[1];
    const float* em    = (const float*)d_in[2];
    const float* pad   = (const float*)d_in[3];
    const float* w_q_w = (const float*)d_in[4];
    const float* w_q_b = (const float*)d_in[5];
    const float* w_k   = (const float*)d_in[6];
    const float* w_v   = (const float*)d_in[7];
    const float* w_h_w = (const float*)d_in[8];
    const float* w_h_b = (const float*)d_in[9];
    const float* b_ks  = (const float*)d_in[10];
    const float* b_vs  = (const float*)d_in[11];

    float* out     = (float*)d_out;                       // (B, LQ, DM) fp32
    float* weights = out + (size_t)NB * LQ * DM;          // (H*B, LQ, LK) fp32

    char* ws = (char*)d_ws;
    unsigned short* qb  = (unsigned short*)(ws + 0);          // 2 MB
    unsigned short* kb  = (unsigned short*)(ws + 2097152);    // 2 MB
    unsigned short* wqb = (unsigned short*)(ws + 4194304);    // 512 KB
    unsigned short* wkb = (unsigned short*)(ws + 4718592);
    unsigned short* wvb = (unsigned short*)(ws + 5242880);
    unsigned short* whb = (unsigned short*)(ws + 5767168);
    unsigned short* Qp  = (unsigned short*)(ws + 6291456);    // 2 MB
    unsigned short* Kp  = (unsigned short*)(ws + 8388608);    // 2 MB
    unsigned short* Vt  = (unsigned short*)(ws + 10485760);   // 2 MB
    unsigned short* Hb  = (unsigned short*)(ws + 12582912);   // 2 MB
    unsigned short* Pk  = (unsigned short*)(ws + 14680064);   // 2 MB

    prep_kernel<<<dim3(1024, 7), 256, 0, stream>>>(q, k, w_q_w, w_k, w_v, w_h_w,
                                                   em, pad, qb, kb, wqb, wkb, wvb, whb, Pk);
    proj_all<<<dim3(32, 8, 3), 256, 0, stream>>>(qb, kb, wqb, wkb, wvb, w_q_b, Qp, Kp, Vt);
    attn_fused<<<dim3(LQ / QT, 32), 512, 0, stream>>>(Qp, Kp, Vt, Pk, b_ks, b_vs, weights, Hb);
    outproj_mfma<<<dim3(32, 8), 256, 0, stream>>>(Hb, whb, w_h_b, out);
}